// Round 1
// baseline (470.189 us; speedup 1.0000x reference)
//
#include <hip/hip_runtime.h>
#include <cstdint>
#include <cstddef>

// ---------------------------------------------------------------------------
// Problem: y = x @ W^T + lb   [B=32768, C=2048], K=2048
//          GroupNorm(32 groups of 64 ch) -> *gw + gb -> min over C per row
//          out[0, c, b, 0] = mins[b] + final_bias[c]   (shape [1,C,B,1])
//
// Plan:
//   k1: convert x  (fp32->bf16) into d_out bytes [0, 128MiB)
//   k1: convert W  (fp32->bf16) into d_out bytes [128MiB, +8MiB)
//   memset: encoded-min buffer = 0xFF (== +inf in monotone encoding),
//           placed at d_out elements [1088*32768, 1089*32768) (the c==1088 row)
//   k2: fused bf16-MFMA GEMM (128x128 tile) + bias + groupnorm + row-min
//       (atomicMin on monotone-encoded uint per row)
//   k3: broadcast out[c*B+b] = dec(mins[b]) + bias[c], skipping c==1088
//   k4: fixup c==1088 (reads its own cell before overwriting)
// ---------------------------------------------------------------------------

#define AS1C(p) ((const __attribute__((address_space(1))) void*)(p))
#define AS3(p)  ((__attribute__((address_space(3))) void*)(p))

typedef short  short8  __attribute__((ext_vector_type(8)));
typedef int    int4v   __attribute__((ext_vector_type(4)));
typedef float  f32x4   __attribute__((ext_vector_type(4)));
typedef unsigned short ushort8 __attribute__((ext_vector_type(8)));

static constexpr int BDIM = 32768;
static constexpr int KDIM = 2048;
static constexpr int CDIM = 2048;

// ----------------------------- helpers -------------------------------------

__device__ __forceinline__ unsigned short f2bf(float f) {
    unsigned u = __float_as_uint(f);
    u += 0x7FFFu + ((u >> 16) & 1u);   // RNE
    return (unsigned short)(u >> 16);
}

__device__ __forceinline__ unsigned enc_min(float f) {
    unsigned u = __float_as_uint(f);
    return (u & 0x80000000u) ? ~u : (u | 0x80000000u);  // monotone float->uint
}

__device__ __forceinline__ float dec_min(unsigned e) {
    unsigned u = (e & 0x80000000u) ? (e ^ 0x80000000u) : ~e;
    return __uint_as_float(u);
}

// ----------------------------- k1: convert ---------------------------------

__global__ void convert_kernel(const float* __restrict__ src,
                               unsigned short* __restrict__ dst, int n8) {
    int i = blockIdx.x * blockDim.x + threadIdx.x;
    if (i >= n8) return;
    const float4* s4 = (const float4*)src;
    float4 a = s4[2 * i];
    float4 b = s4[2 * i + 1];
    ushort8 o;
    o[0] = f2bf(a.x); o[1] = f2bf(a.y); o[2] = f2bf(a.z); o[3] = f2bf(a.w);
    o[4] = f2bf(b.x); o[5] = f2bf(b.y); o[6] = f2bf(b.z); o[7] = f2bf(b.w);
    ((ushort8*)dst)[i] = o;
}

// ------------------- k2: fused GEMM + GroupNorm + row-min -------------------
// 128x128 tile, BK=64, 4 waves (2x2), each wave owns a 64x64 subtile whose
// 64 columns are exactly one GroupNorm group.

__global__ __launch_bounds__(256) void gemm_gn_min(
    const unsigned short* __restrict__ Abf,   // x   [32768,2048] bf16
    const unsigned short* __restrict__ Wbf,   // W   [2048,2048]  bf16
    const float* __restrict__ lb,             // linear bias [C]
    const float* __restrict__ gw,             // gn weight   [C]
    const float* __restrict__ gb,             // gn bias     [C]
    unsigned int* mins_enc)                   // [B] encoded row mins
{
    __shared__ unsigned char lds[32768];      // A tile 16KB | B tile 16KB

    const int tid  = threadIdx.x;
    const int wid  = tid >> 6;
    const int lane = tid & 63;
    const int bj   = blockIdx.x & 15;         // column tile (C/128 = 16)
    const int bi   = blockIdx.x >> 4;         // row tile    (B/128 = 256)
    const int row0 = bi * 128, col0 = bj * 128;
    const int wr = wid >> 1, wc = wid & 1;

    f32x4 acc[4][4] = {};

    // staging: wave `wid` stages rows [wid*32, wid*32+32) of both tiles.
    // global_load_lds writes linearly (base + lane*16); we pre-swizzle the
    // GLOBAL chunk so that LDS physical chunk p of row r holds logical chunk
    // p ^ (r&7)  (rule #21: linear dest + inverse-swizzled source).
    const int srow   = lane >> 3;                 // 0..7 row within 8-row call
    const int schunk = (lane & 7) ^ srow;         // swizzled 16B-chunk index
    const unsigned short* gA0 =
        Abf + (size_t)(row0 + wid * 32 + srow) * KDIM + schunk * 8;
    const unsigned short* gB0 =
        Wbf + (size_t)(col0 + wid * 32 + srow) * KDIM + schunk * 8;

    const int lrow = lane & 15;   // fragment row/col within 16
    const int lq   = lane >> 4;   // 0..3
    const int lx   = lane & 7;    // read-side XOR (matches r&7 of target row)

    for (int kt = 0; kt < KDIM / 64; ++kt) {
#pragma unroll
        for (int j = 0; j < 4; ++j) {
            __builtin_amdgcn_global_load_lds(
                AS1C(gA0 + (size_t)j * 8 * KDIM + kt * 64),
                AS3(&lds[(wid * 32 + j * 8) * 128]), 16, 0, 0);
            __builtin_amdgcn_global_load_lds(
                AS1C(gB0 + (size_t)j * 8 * KDIM + kt * 64),
                AS3(&lds[16384 + (wid * 32 + j * 8) * 128]), 16, 0, 0);
        }
        __syncthreads();

#pragma unroll
        for (int ks = 0; ks < 2; ++ks) {
            int4v af[4], bfr[4];
            const int ch = (ks * 4 + lq) ^ lx;    // swizzled read chunk
#pragma unroll
            for (int m = 0; m < 4; ++m) {
                int r = wr * 64 + m * 16 + lrow;
                af[m] = *(const int4v*)(&lds[r * 128 + ch * 16]);
            }
#pragma unroll
            for (int n = 0; n < 4; ++n) {
                int r = wc * 64 + n * 16 + lrow;
                bfr[n] = *(const int4v*)(&lds[16384 + r * 128 + ch * 16]);
            }
#pragma unroll
            for (int m = 0; m < 4; ++m)
#pragma unroll
                for (int n = 0; n < 4; ++n)
                    acc[m][n] = __builtin_amdgcn_mfma_f32_16x16x32_bf16(
                        __builtin_bit_cast(short8, af[m]),
                        __builtin_bit_cast(short8, bfr[n]),
                        acc[m][n], 0, 0, 0);
        }
        __syncthreads();
    }

    // ---- epilogue: +linear_bias, groupnorm over this wave's 64 cols (one
    // group), min over group, atomicMin into per-row global min.
    // C/D layout (16x16x32): col = lane&15, row = (lane>>4)*4 + reg.
    float lbv[4], gwv[4], gbv[4];
    const int cbase = col0 + wc * 64 + lrow;
#pragma unroll
    for (int n = 0; n < 4; ++n) {
        int c = cbase + n * 16;
        lbv[n] = lb[c]; gwv[n] = gw[c]; gbv[n] = gb[c];
    }

#pragma unroll
    for (int m = 0; m < 4; ++m) {
#pragma unroll
        for (int i = 0; i < 4; ++i) {
            float v[4];
            float s1 = 0.f, s2 = 0.f;
#pragma unroll
            for (int n = 0; n < 4; ++n) {
                v[n] = acc[m][n][i] + lbv[n];
                s1 += v[n];
                s2 += v[n] * v[n];
            }
#pragma unroll
            for (int mask = 1; mask <= 8; mask <<= 1) {
                s1 += __shfl_xor(s1, mask, 64);
                s2 += __shfl_xor(s2, mask, 64);
            }
            float mean = s1 * (1.f / 64.f);
            float var  = s2 * (1.f / 64.f) - mean * mean;
            float rstd = rsqrtf(var + 1e-5f);
            float mn = 3.4e38f;
#pragma unroll
            for (int n = 0; n < 4; ++n) {
                float nv = (v[n] - mean) * rstd * gwv[n] + gbv[n];
                mn = fminf(mn, nv);
            }
#pragma unroll
            for (int mask = 1; mask <= 8; mask <<= 1)
                mn = fminf(mn, __shfl_xor(mn, mask, 64));
            if (lrow == 0) {
                int row = row0 + wr * 64 + m * 16 + lq * 4 + i;
                atomicMin(mins_enc + row, enc_min(mn));
            }
        }
    }
}

// --------------------------- k3: broadcast ----------------------------------

__global__ void finalize_kernel(const unsigned int* mins_enc,
                                const float* __restrict__ fb, float* out) {
    size_t t = (size_t)blockIdx.x * 256 + threadIdx.x;
    size_t flat = t * 4;                      // 4 consecutive b, same c
    int c = (int)(flat >> 15);
    if (c == 1088) return;                    // mins live here; fixup later
    int b = (int)(flat & 32767);
    uint4 e = *(const uint4*)(mins_enc + b);
    float bias = fb[c];
    float4 o;
    o.x = dec_min(e.x) + bias;
    o.y = dec_min(e.y) + bias;
    o.z = dec_min(e.z) + bias;
    o.w = dec_min(e.w) + bias;
    *(float4*)(out + flat) = o;
}

__global__ void fixup_kernel(const float* __restrict__ fb, float* out) {
    int b = blockIdx.x * 256 + threadIdx.x;
    size_t idx = (size_t)1088 * 32768 + b;
    unsigned e = ((const unsigned*)out)[idx];  // read own cell first
    out[idx] = dec_min(e) + fb[1088];
}

// ----------------------------- launcher -------------------------------------

extern "C" void kernel_launch(void* const* d_in, const int* in_sizes, int n_in,
                              void* d_out, int out_size, void* d_ws, size_t ws_size,
                              hipStream_t stream) {
    const float* x  = (const float*)d_in[0];
    const float* w  = (const float*)d_in[1];
    const float* lb = (const float*)d_in[2];
    const float* gw = (const float*)d_in[3];
    const float* gb = (const float*)d_in[4];
    const float* fb = (const float*)d_in[5];
    float* out = (float*)d_out;

    // scratch regions inside d_out (268 MB total):
    unsigned short* xb = (unsigned short*)d_out;                        // 128 MiB
    unsigned short* wb = (unsigned short*)((char*)d_out + 134217728);   //   8 MiB
    unsigned int* mins = (unsigned int*)((char*)d_out + (size_t)1088 * 32768 * 4);

    // k1: fp32 -> bf16
    {
        int n8 = (BDIM * KDIM) / 8;   // 8388608
        convert_kernel<<<(n8 + 255) / 256, 256, 0, stream>>>(x, xb, n8);
    }
    {
        int n8 = (CDIM * KDIM) / 8;   // 524288
        convert_kernel<<<(n8 + 255) / 256, 256, 0, stream>>>(w, wb, n8);
    }

    // init encoded mins to 0xFFFFFFFF (>= every encoding)
    hipMemsetAsync((void*)mins, 0xFF, (size_t)BDIM * 4, stream);

    // k2: fused GEMM + GN + min
    gemm_gn_min<<<dim3((BDIM / 128) * (CDIM / 128)), dim3(256), 0, stream>>>(
        xb, wb, lb, gw, gb, mins);

    // k3: broadcast (skips c==1088), then fixup c==1088
    finalize_kernel<<<(BDIM / 4) * CDIM / 256, 256, 0, stream>>>(mins, fb, out);
    fixup_kernel<<<BDIM / 256, 256, 0, stream>>>(fb, out);
}